// Round 20
// baseline (331.327 us; speedup 1.0000x reference)
//
#include <hip/hip_runtime.h>

// RATSQL relation-aware transformer layer, MI355X.
// Round 39: XCD-locality swizzle (T1) on attn. R38: 330.9us best. attn
// FETCH 9.9MB vs ~5-6MB unique -> (b,h) K/V panels re-fetched: default
// round-robin dispatch spreads each (b,h)'s 128 blocks over all 8 XCDs, so
// every 4MB XCD-L2 must hold all 16 panels + relc2 -> thrash; K/V loads
// (the latency-bound inner loops) partially miss to HBM (~900cy vs ~200).
// Fix: decode blockIdx.x as xcd=bid&7, seq=bid>>3, gh=xcd*2+(seq>>7),
// tile=seq&127 -> each XCD owns 2 (b,h) groups (same b -> shared relc2[b]).
// Bijective 8x2x128=2048; pure permutation, zero numerics change.
// All else identical to R38.

typedef unsigned short ushortt;
typedef __attribute__((ext_vector_type(8))) short short8;
typedef __attribute__((ext_vector_type(4))) float f32x4;

__device__ __forceinline__ ushortt f2bf(float f) {
  union { float f; unsigned int u; } c; c.f = f;
  unsigned int r = c.u + 0x7fffu + ((c.u >> 16) & 1u);
  return (ushortt)(r >> 16);
}
__device__ __forceinline__ unsigned int pk2(float a, float b) {
  return (unsigned int)f2bf(a) | ((unsigned int)f2bf(b) << 16);
}

// ---------- fused setup: relpack (bids 0..2047), cvt_bf (2048..2303),
// wcvt (2304..5375). All independent streams of work. ----------
__global__ __launch_bounds__(256) void setup_k(
    const float* __restrict__ Wq, const float* __restrict__ Wk,
    const float* __restrict__ Wv, const float* __restrict__ Wo,
    const float* __restrict__ W1, const float* __restrict__ W2,
    ushortt* __restrict__ wbuf,
    const int* __restrict__ rel, const int* __restrict__ msk,
    unsigned char* __restrict__ relc2,
    const float* __restrict__ Ev, float* __restrict__ EvT,
    const float* __restrict__ Ek, ushortt* __restrict__ ekbf,
    const float* __restrict__ inp, ushortt* __restrict__ inpbf) {
  int bid = blockIdx.x;
  int tid = threadIdx.x;
  if (bid < 2048) {
    // relpack: g in [0, 524288)
    int g = bid * 256 + tid;
    const int4* r4 = (const int4*)rel;
    const int4* m4 = (const int4*)msk;
    int4 r = r4[g];
    int4 m = m4[g];
    int b = g >> 18;
    int rem = g & 262143;
    int i = rem >> 8;
    int j4 = (rem & 255) << 2;
    size_t base = ((size_t)b << 20) + ((size_t)(i >> 3) << 13) + (i & 7);
    relc2[base + ((size_t)(j4 + 0) << 3)] = (unsigned char)(m.x ? 128 : r.x);
    relc2[base + ((size_t)(j4 + 1) << 3)] = (unsigned char)(m.y ? 128 : r.y);
    relc2[base + ((size_t)(j4 + 2) << 3)] = (unsigned char)(m.z ? 128 : r.z);
    relc2[base + ((size_t)(j4 + 3) << 3)] = (unsigned char)(m.w ? 128 : r.w);
    if (g < 3200) {
      int d = g / 100, rr = g - d * 100;
      EvT[d * 100 + rr] = Ev[(rr << 5) + d];
    }
    if (g < 3584) {
      int rr = g >> 5, d = g & 31;
      ekbf[g] = (rr < 100) ? f2bf(Ek[(rr << 5) + d]) : (ushortt)0;
    }
  } else if (bid < 2304) {
    // cvt_bf: inp fp32 -> bf16, 524288 elems, 8/thread
    int idx = ((bid - 2048) * 256 + tid) * 8;
    float4 f0 = *(const float4*)(inp + idx);
    float4 f1 = *(const float4*)(inp + idx + 4);
    uint4 u;
    u.x = pk2(f0.x, f0.y); u.y = pk2(f0.z, f0.w);
    u.z = pk2(f1.x, f1.y); u.w = pk2(f1.z, f1.w);
    *(uint4*)(inpbf + idx) = u;
  } else {
    // wcvt: both layers' six weights -> [N][K] bf16
    int i = (bid - 2304) * 256 + tid;
    int st = 3072 * 256;
    for (; i < 1572864; i += st) {
      int l = (i >= 786432) ? 1 : 0;
      int e = i - (l ? 786432 : 0);
      size_t o_w = (size_t)l * 65536, o_w1 = (size_t)l * 262144;
      float v;
      if (e < 262144) {
        int which = e >> 16;
        int loc = e & 65535;
        int k = loc & 255, n = loc >> 8;
        const float* W = (which == 0) ? Wq : (which == 1) ? Wk
                       : (which == 2) ? Wv : Wo;
        v = W[o_w + ((size_t)k << 8) + n];
      } else if (e < 524288) {
        int loc = e - 262144;
        int k = loc & 255, n = loc >> 8;
        v = W1[o_w1 + ((size_t)k << 10) + n];
      } else {
        int loc = e - 524288;
        int k = loc & 1023, n = loc >> 10;
        v = W2[o_w1 + ((size_t)k << 8) + n];
      }
      wbuf[i] = f2bf(v);
    }
  }
}

// ---------- MFMA GEMM body: 64x64 tile, 4 waves, BK=64, reg double-buffer ----
// kvmode 0: C fp32 / cbf bf16 row-major. 1: bf16 [d][j] (v). 2: bf16 [j][d] (k).
// 3: cbf bf16 [i][d] pre-scaled only (q; no fp32 write).
__device__ __forceinline__ void mgemm_body(
    const ushortt* __restrict__ A, const ushortt* __restrict__ BT,
    const float* __restrict__ bias, size_t boff,
    float* __restrict__ C, ushortt* __restrict__ cbf,
    int m0, int n0, int N, int K, int kbeg, int kend, int relu, int kvmode)
{
  __shared__ ushortt As[64 * 72];   // 9.2 KB, +8 pad keeps b128 reads 2-way max
  __shared__ ushortt Bs[64 * 72];
  int tid = threadIdx.x;
  int wv = tid >> 6, lane = tid & 63;
  int quad = lane >> 4, mr = lane & 15;
  int sm = tid >> 2, k16 = (tid & 3) << 4;

  const ushortt* ap = A + (size_t)(m0 + sm) * K + k16;
  const ushortt* bp = BT + (size_t)(n0 + sm) * K + k16;

  // prefetch round 0
  uint4 ra0 = *(const uint4*)(ap + kbeg);
  uint4 ra1 = *(const uint4*)(ap + kbeg + 8);
  uint4 rb0 = *(const uint4*)(bp + kbeg);
  uint4 rb1 = *(const uint4*)(bp + kbeg + 8);

  f32x4 acc[4] = {};
  for (int k0 = kbeg; k0 < kend; k0 += 64) {
    *(uint4*)(&As[sm * 72 + k16])     = ra0;
    *(uint4*)(&As[sm * 72 + k16 + 8]) = ra1;
    *(uint4*)(&Bs[sm * 72 + k16])     = rb0;
    *(uint4*)(&Bs[sm * 72 + k16 + 8]) = rb1;
    __syncthreads();
    if (k0 + 64 < kend) {   // issue next round; waits hide under MFMAs
      ra0 = *(const uint4*)(ap + k0 + 64);
      ra1 = *(const uint4*)(ap + k0 + 72);
      rb0 = *(const uint4*)(bp + k0 + 64);
      rb1 = *(const uint4*)(bp + k0 + 72);
    }
#pragma unroll
    for (int kh = 0; kh < 2; ++kh) {
      short8 af = *(const short8*)(&As[(wv * 16 + mr) * 72 + (kh << 5) + quad * 8]);
#pragma unroll
      for (int nt = 0; nt < 4; ++nt) {
        short8 bf = *(const short8*)(&Bs[(nt * 16 + mr) * 72 + (kh << 5) + quad * 8]);
        acc[nt] = __builtin_amdgcn_mfma_f32_16x16x32_bf16(af, bf, acc[nt], 0, 0, 0);
      }
    }
    __syncthreads();
  }
#pragma unroll
  for (int nt = 0; nt < 4; ++nt) {
#pragma unroll
    for (int r = 0; r < 4; ++r) {
      int m = m0 + wv * 16 + quad * 4 + r;
      int n = n0 + nt * 16 + mr;
      float v = acc[nt][r];
      if (bias) v += bias[boff + n];
      if (relu) v = fmaxf(v, 0.f);
      if (kvmode == 3) {
        int b = m >> 10, i = m & 1023, h = n >> 5, d = n & 31;
        cbf[(size_t)(((b << 3) + h) * 1024 + i) * 32 + d] =
            f2bf(v * 0.17677669529663687f);
      } else if (kvmode == 1) {
        int b = m >> 10, i = m & 1023, h = n >> 5, d = n & 31;
        cbf[(size_t)(((b << 3) + h) * 32 + d) * 1024 + i] = f2bf(v);
      } else if (kvmode == 2) {
        int b = m >> 10, i = m & 1023, h = n >> 5, d = n & 31;
        cbf[(size_t)(((b << 3) + h) * 1024 + i) * 32 + d] = f2bf(v);
      } else if (cbf) {
        cbf[(size_t)m * N + n] = f2bf(v);
      } else {
        C[(size_t)m * N + n] = v;
      }
    }
  }
}

// split-K aware: gridDim.z = ksplit (1,2,4); z=0 -> C0 (+bias), z>0 -> Cz
__global__ __launch_bounds__(256) void mgemm_k(
    const ushortt* __restrict__ A, const ushortt* __restrict__ BT,
    const float* __restrict__ bias, size_t boff,
    float* __restrict__ C0, float* __restrict__ C1,
    float* __restrict__ C2, float* __restrict__ C3,
    ushortt* __restrict__ cbf, int N, int K, int relu)
{
  int kidx = blockIdx.z;
  int kc = K / gridDim.z;
  int kbeg = kidx * kc;
  float* C = (kidx == 0) ? C0 : (kidx == 1) ? C1 : (kidx == 2) ? C2 : C3;
  mgemm_body(A, BT, kidx ? nullptr : bias, boff, C, cbf,
             blockIdx.y * 64, blockIdx.x * 64, N, K, kbeg, kbeg + kc, relu, 0);
}

// fused QKV: sel 0 -> qbf bf16 scaled [i][d]; 1 -> k bf16 [j][d]; 2 -> v bf16 [d][j]
__global__ __launch_bounds__(256) void mqkv_k(
    const ushortt* __restrict__ xbf, const ushortt* __restrict__ WT,
    ushortt* __restrict__ qbf, ushortt* __restrict__ kbf,
    ushortt* __restrict__ vTbf)
{
  int sel = blockIdx.x >> 2;
  const ushortt* BT = WT + (size_t)sel * 65536;
  int mode = (sel == 0) ? 3 : (sel == 1) ? 2 : 1;
  mgemm_body(xbf, BT, nullptr, 0, nullptr,
             (sel == 0) ? qbf : (sel == 1) ? kbf : vTbf,
             blockIdx.y * 64, (blockIdx.x & 3) * 64, 256, 256, 0, 256, 0, mode);
}

// ---------- MFMA attention: block = (b, h, 8 i's), 4 waves, ~23.1 KB LDS ----
// XCD-locality swizzle: xcd=bid&7 owns 2 (b,h) groups (same b) -> K/V/relc2
// L2-resident per XCD. expq via MFMA from ekbf; no Ek/qs staging phase.
__global__ __launch_bounds__(256) void attn_mf8_k(
    const ushortt* __restrict__ qbf, const ushortt* __restrict__ kbf,
    const ushortt* __restrict__ vTbf, const ushortt* __restrict__ ekbf,
    const float* __restrict__ EvT, const unsigned char* __restrict__ relc2,
    ushortt* __restrict__ out)
{
  __shared__ __align__(16) ushortt pbf[8 * 1028];  // 16.4 KB
  __shared__ float expq[800];          // 3.2 KB; pvpart/pvtot overlay after (3)
  __shared__ float wbin[8 * 108];      // 3.4 KB; stride 108: 16B-aligned rows

  int tid = threadIdx.x;
  int wv = tid >> 6, lane = tid & 63;
  int quad = lane >> 4, mr = lane & 15;
  // XCD-locality decode (bijective over 2048): each XCD -> 2 (b,h) groups
  int raw = blockIdx.x;
  int xcd = raw & 7;
  int seq = raw >> 3;                  // 0..255
  int gh = (xcd << 1) + (seq >> 7);    // 0..15 = b*8+h
  int tile = seq & 127;
  int h = gh & 7;
  int b = gh >> 3;
  int i0 = tile << 3;

  // rel codes: relc2[b][tile][j][i8]; lane's 4 rows per iter = one dword.
  int iqsel = quad & 1;
  int iq = iqsel << 2;
  int jofs = ((quad >> 1) << 4) + mr;
  int jbase = wv << 8;
  const unsigned int* rc2 =
      (const unsigned int*)(relc2 + (((size_t)(b << 7) + tile) << 13));
  unsigned int rcw[8];
#pragma unroll
  for (int t = 0; t < 8; ++t)
    rcw[t] = rc2[(((jbase + (t << 5) + jofs)) << 1) + iqsel];

  for (int p = tid; p < 864; p += 256) wbin[p] = 0.f;

  // q frag: one 16B load (qbf pre-scaled bf16, rows 8..15 dup rows 0..7)
  const ushortt* qsrc = qbf + ((size_t)gh << 15);
  short8 qf = *(const short8*)(qsrc + (((size_t)i0 + (mr & 7)) << 5) + quad * 8);

  const ushortt* ks = kbf + ((size_t)gh << 15);   // [j][d]
  const ushortt* vs = vTbf + ((size_t)gh << 15);  // [d][j]
  short8 kfa = *(const short8*)(ks + ((size_t)(jbase + mr) << 5) + quad * 8);
  short8 kfb = *(const short8*)(ks + ((size_t)(jbase + 16 + mr) << 5) + quad * 8);

  // expq via MFMA: r-tiles of 16; wave wv does rt = wv, wv+4 (7 tiles total).
  // C layout: lane holds C[i=quad*4+reg][r=mr]; quads 2,3 dup (A rows 8-15).
#pragma unroll
  for (int tsel = 0; tsel < 2; ++tsel) {
    int rt = wv + (tsel << 2);
    if (rt <= 6) {
      int r0 = rt << 4;
      short8 ekf = *(const short8*)(ekbf + ((size_t)(r0 + mr) << 5) + quad * 8);
      f32x4 z = {};
      f32x4 eq = __builtin_amdgcn_mfma_f32_16x16x32_bf16(qf, ekf, z, 0, 0, 0);
      if (quad < 2) {
#pragma unroll
        for (int r = 0; r < 4; ++r) {
          int i = quad * 4 + r;
          int rr = r0 + mr;
          if (rr < 100) expq[i * 100 + rr] = __expf(eq[r]);
        }
      }
    }
  }
  __syncthreads();  // (1) expq + wbin ready

  // ---- scores: wave wv covers j-quarter (256 j's) as 8 double-tiles ----
#pragma unroll
  for (int t = 0; t < 8; ++t) {
    int j0 = jbase + (t << 5);
    short8 ka = kfa, kb = kfb;
    if (t < 7) {
      kfa = *(const short8*)(ks + ((size_t)(j0 + 32 + mr) << 5) + quad * 8);
      kfb = *(const short8*)(ks + ((size_t)(j0 + 48 + mr) << 5) + quad * 8);
    }
    f32x4 z = {};
    f32x4 sa = __builtin_amdgcn_mfma_f32_16x16x32_bf16(qf, ka, z, 0, 0, 0);
    f32x4 sb = __builtin_amdgcn_mfma_f32_16x16x32_bf16(qf, kb, z, 0, 0, 0);
    int j = j0 + jofs;
    unsigned int w = rcw[t];
#pragma unroll
    for (int r = 0; r < 4; ++r) {
      int i = iq + r;
      float sv = (quad >= 2) ? sb[r] : sa[r];
      unsigned int c = (w >> (r << 3)) & 255u;
      float p = 0.f;
      if (c < 128u) {
        p = __expf(sv) * expq[i * 100 + (int)c];
        atomicAdd(&wbin[i * 108 + (int)c], p);
      }
      pbf[i * 1028 + j] = f2bf(p);
    }
  }
  __syncthreads();  // (3) pbf, wbin complete

  // ---- PV: ntile = wv&1 (d0), khalf = wv>>1 (k0); A rows 8..15 alias 0..7 ----
  float* pvpart = expq;        // [2][8][16]
  float* pvtot  = expq + 256;  // [8][32]
  int d0 = (wv & 1) << 4;
  int k0 = (wv >> 1) << 9;
  int prow = (mr & 7) * 1028;
  f32x4 acc0 = {}, acc1 = {};
  short8 vf = *(const short8*)(vs + ((size_t)(d0 + mr) << 10) + k0 + quad * 8);
#pragma unroll
  for (int kt = 0; kt < 16; ++kt) {
    int kk = k0 + (kt << 5);
    short8 vcur = vf;
    if (kt < 15)
      vf = *(const short8*)(vs + ((size_t)(d0 + mr) << 10) + k0 + ((kt + 1) << 5) + quad * 8);
    short8 pf = *(const short8*)(&pbf[prow + kk + quad * 8]);
    if (kt & 1)
      acc1 = __builtin_amdgcn_mfma_f32_16x16x32_bf16(pf, vcur, acc1, 0, 0, 0);
    else
      acc0 = __builtin_amdgcn_mfma_f32_16x16x32_bf16(pf, vcur, acc0, 0, 0, 0);
  }
  f32x4 acc;
#pragma unroll
  for (int r = 0; r < 4; ++r) acc[r] = acc0[r] + acc1[r];
  if (wv >= 2 && quad < 2) {
#pragma unroll
    for (int r = 0; r < 4; ++r)
      pvpart[((wv & 1) << 7) + (quad * 4 + r) * 16 + mr] = acc[r];
  }
  __syncthreads();  // (4)
  if (wv < 2 && quad < 2) {
#pragma unroll
    for (int r = 0; r < 4; ++r) {
      int i = quad * 4 + r;
      pvtot[i * 32 + d0 + mr] = acc[r] + pvpart[((wv & 1) << 7) + i * 16 + mr];
    }
  }
  __syncthreads();  // (5)

  // ---- final: all 256 threads, i = tid>>5, d = tid&31; bf16 out ----
  // denom[i] = sum of all bins (each unmasked p lands in exactly one bin).
  {
    int i = tid >> 5, d = tid & 31;
    const float4* evt = (const float4*)(EvT + d * 100);
    const float4* wb4 = (const float4*)(&wbin[i * 108]);
    float e0 = 0.f, e1 = 0.f, e2 = 0.f, e3 = 0.f;
    float s0 = 0.f, s1 = 0.f, s2 = 0.f, s3 = 0.f;
#pragma unroll
    for (int rq = 0; rq < 25; ++rq) {
      float4 e4 = evt[rq];
      float4 w4 = wb4[rq];
      e0 += w4.x * e4.x; s0 += w4.x;
      e1 += w4.y * e4.y; s1 += w4.y;
      e2 += w4.z * e4.z; s2 += w4.z;
      e3 += w4.w * e4.w; s3 += w4.w;
    }
    float ev = (e0 + e1) + (e2 + e3);
    float den = (s0 + s1) + (s2 + s3);
    out[(((size_t)(b * 1024 + i0 + i) * 8 + h) << 5) + d] =
        f2bf((pvtot[i * 32 + d] + ev) / den);
  }
}

// ---------- residual (+ up to 4 partials) + LayerNorm: one wave per row ----
__global__ __launch_bounds__(256) void ln_k(
    const float* __restrict__ x, const float* __restrict__ o,
    const float* __restrict__ o2, const float* __restrict__ o3,
    const float* __restrict__ o4,
    const float* __restrict__ g, const float* __restrict__ bta, size_t eoff,
    float* __restrict__ xo, ushortt* __restrict__ xbf, float* __restrict__ fout)
{
  int tid = threadIdx.x;
  int lane = tid & 63;
  int row = (blockIdx.x << 2) + (tid >> 6);
  int col = lane << 2;
  size_t base = (size_t)row * 256 + col;

  float4 r = *(const float4*)(x + base);
  float4 ov = *(const float4*)(o + base);
  r.x += ov.x; r.y += ov.y; r.z += ov.z; r.w += ov.w;
  if (o2) {
    float4 v2 = *(const float4*)(o2 + base);
    r.x += v2.x; r.y += v2.y; r.z += v2.z; r.w += v2.w;
  }
  if (o3) {
    float4 v3 = *(const float4*)(o3 + base);
    r.x += v3.x; r.y += v3.y; r.z += v3.z; r.w += v3.w;
  }
  if (o4) {
    float4 v4 = *(const float4*)(o4 + base);
    r.x += v4.x; r.y += v4.y; r.z += v4.z; r.w += v4.w;
  }
  float s = (r.x + r.y) + (r.z + r.w);
  s += __shfl_xor(s, 1, 64);
  s += __shfl_xor(s, 2, 64);
  s += __shfl_xor(s, 4, 64);
  s += __shfl_xor(s, 8, 64);
  s += __shfl_xor(s, 16, 64);
  s += __shfl_xor(s, 32, 64);
  float mean = s * (1.f / 256.f);
  float dx = r.x - mean, dy = r.y - mean, dz = r.z - mean, dw = r.w - mean;
  float sq = (dx * dx + dy * dy) + (dz * dz + dw * dw);
  sq += __shfl_xor(sq, 1, 64);
  sq += __shfl_xor(sq, 2, 64);
  sq += __shfl_xor(sq, 4, 64);
  sq += __shfl_xor(sq, 8, 64);
  sq += __shfl_xor(sq, 16, 64);
  sq += __shfl_xor(sq, 32, 64);
  float rs = rsqrtf(sq * (1.f / 256.f) + 1e-5f);
  float4 gv = *(const float4*)(g + eoff + col);
  float4 bv = *(const float4*)(bta + eoff + col);
  float4 val;
  val.x = dx * rs * gv.x + bv.x;
  val.y = dy * rs * gv.y + bv.y;
  val.z = dz * rs * gv.z + bv.z;
  val.w = dw * rs * gv.w + bv.w;
  *(float4*)(xo + base) = val;
  uint2 u;
  u.x = pk2(val.x, val.y);
  u.y = pk2(val.z, val.w);
  *(uint2*)(xbf + base) = u;
  if (fout) *(float4*)(fout + base) = val;
}

extern "C" void kernel_launch(void* const* d_in, const int* in_sizes, int n_in,
                              void* d_out, int out_size, void* d_ws, size_t ws_size,
                              hipStream_t stream) {
  const float* inp  = (const float*)d_in[0];
  const float* Wq   = (const float*)d_in[1];
  const float* Wk   = (const float*)d_in[2];
  const float* Wv   = (const float*)d_in[3];
  const float* Wo   = (const float*)d_in[4];
  const float* bo   = (const float*)d_in[5];
  const float* W1   = (const float*)d_in[6];
  const float* b1   = (const float*)d_in[7];
  const float* W2   = (const float*)d_in[8];
  const float* b2   = (const float*)d_in[9];
  const float* ln1g = (const float*)d_in[10];
  const float* ln1b = (const float*)d_in[11];
  const float* ln2g = (const float*)d_in[12];
  const float* ln2b = (const float*)d_in[13];
  const float* Ek   = (const float*)d_in[14];
  const float* Ev   = (const float*)d_in[15];
  const int*   rel  = (const int*)d_in[16];
  const int*   msk  = (const int*)d_in[17];

  const size_t SZ = 524288;  // 2048*256
  float* x        = (float*)d_ws;               // 2 MB fp32
  float* q        = x + SZ;                     // 2 MB fp32 (dead; layout keep)
  ushortt* kbf    = (ushortt*)(q + SZ);         // 1 MB bf16 [j][d]
  ushortt* vTbf   = kbf + SZ;                   // 1 MB bf16 [d][j]
  ushortt* attnbf = vTbf + SZ;                  // 1 MB bf16 attn out
  ushortt* xbf    = attnbf + SZ;                // 1 MB bf16 x
  float* tmp      = (float*)(xbf + SZ);         // 2 MB fp32 partial 0
  ushortt* wbuf   = (ushortt*)(tmp + SZ);       // 3 MB (both layers' weights)
  unsigned char* relc2 = (unsigned char*)(wbuf + 1572864);  // 2 MB packed rel
  float* EvT      = (float*)(relc2 + 2097152);  // 12.8 KB (pad to 16 KB)
  float* tmp2     = (float*)((char*)EvT + 16384); // 2 MB fp32 partial 1
  ushortt* inpbf  = (ushortt*)tmp2;             // alias: dead before wo writes tmp2
  ushortt* qbf    = (ushortt*)(tmp2 + SZ);      // 1 MB bf16 q (scaled)
  ushortt* ekbf   = qbf + SZ;                   // 7 KB bf16 Ek [112][32]
  float* tmp3     = (float*)((char*)ekbf + 16384); // 2 MB fp32 partial 2
  float* tmp4     = tmp3 + SZ;                  // 2 MB fp32 partial 3
  ushortt* ffh    = (ushortt*)q;                // 4 MB alias over q+kbf+vTbf

  dim3 blk(256);
  setup_k<<<5376, blk, 0, stream>>>(Wq, Wk, Wv, Wo, W1, W2, wbuf,
                                    rel, msk, relc2, Ev, EvT, Ek, ekbf,
                                    inp, inpbf);

  for (int l = 0; l < 2; ++l) {
    size_t o_b  = (size_t)l * 256;
    size_t o_b1 = (size_t)l * 1024;
    const ushortt* xinbf = (l == 0) ? inpbf : xbf;
    const float* xin = (l == 0) ? inp : x;
    ushortt* wl = wbuf + (size_t)l * 786432;

    mqkv_k<<<dim3(12, 32), blk, 0, stream>>>(xinbf, wl, qbf, kbf, vTbf);

    attn_mf8_k<<<2048, blk, 0, stream>>>(qbf, kbf, vTbf, ekbf, EvT,
                                         relc2, attnbf);

    // wo-proj: split-K x4 -> 512 blocks, 1 K-round each
    mgemm_k<<<dim3(4, 32, 4), blk, 0, stream>>>(attnbf, wl + 196608,
                                                bo, o_b, tmp, tmp2, tmp3, tmp4,
                                                nullptr, 256, 256, 0);
    ln_k<<<512, blk, 0, stream>>>(xin, tmp, tmp2, tmp3, tmp4,
                                  ln1g, ln1b, o_b, x, xbf, nullptr);

    mgemm_k<<<dim3(16, 32, 1), blk, 0, stream>>>(xbf, wl + 262144,
                                                 b1, o_b1, nullptr, nullptr,
                                                 nullptr, nullptr, ffh,
                                                 1024, 256, 1);
    // ffn2: split-K x4 -> 512 blocks, 4 K-rounds each
    mgemm_k<<<dim3(4, 32, 4), blk, 0, stream>>>(ffh, wl + 524288,
                                                b2, o_b, tmp, tmp2, tmp3, tmp4,
                                                nullptr, 256, 1024, 0);
    ln_k<<<512, blk, 0, stream>>>(x, tmp, tmp2, tmp3, tmp4,
                                  ln2g, ln2b, o_b, x, xbf,
                                  (l == 1) ? (float*)d_out : nullptr);
  }
}

// Round 22
// 325.627 us; speedup vs baseline: 1.0175x; 1.0175x over previous
//
#include <hip/hip_runtime.h>

// RATSQL relation-aware transformer layer, MI355X.
// Round 41 = Round 40 resubmit (container infra failure, no counters; same
// precedent as R21/R35 -> resubmit). Theory unchanged: coalesced weight
// transpose in setup_k. R39: attn FETCH 9.9->5.8MB (L2-thrash mechanism
// confirmed) but duration flat -> attn structurally converged; swizzle kept.
// setup_k's wcvt read W[k*N+n] with consecutive threads stepping k = 1-4KB
// stride -> 4B used per 64B line (<=16x overfetch) on 6.3MB of weights,
// serialized ahead of everything. Now: 32x32 LDS-tiled transpose (1536
// tiles over 6 matrices x 2 layers): coalesced fp32 reads, pad-33 LDS
// (conflict-free), coalesced bf16 writes along k. relpack/cvt unchanged;
// grid 5376 -> 3840. All else identical to R39.

typedef unsigned short ushortt;
typedef __attribute__((ext_vector_type(8))) short short8;
typedef __attribute__((ext_vector_type(4))) float f32x4;

__device__ __forceinline__ ushortt f2bf(float f) {
  union { float f; unsigned int u; } c; c.f = f;
  unsigned int r = c.u + 0x7fffu + ((c.u >> 16) & 1u);
  return (ushortt)(r >> 16);
}
__device__ __forceinline__ unsigned int pk2(float a, float b) {
  return (unsigned int)f2bf(a) | ((unsigned int)f2bf(b) << 16);
}

// ---------- fused setup: relpack (bids 0..2047), cvt_bf (2048..2303),
// wcvt transpose tiles (2304..3839). ----------
__global__ __launch_bounds__(256) void setup_k(
    const float* __restrict__ Wq, const float* __restrict__ Wk,
    const float* __restrict__ Wv, const float* __restrict__ Wo,
    const float* __restrict__ W1, const float* __restrict__ W2,
    ushortt* __restrict__ wbuf,
    const int* __restrict__ rel, const int* __restrict__ msk,
    unsigned char* __restrict__ relc2,
    const float* __restrict__ Ev, float* __restrict__ EvT,
    const float* __restrict__ Ek, ushortt* __restrict__ ekbf,
    const float* __restrict__ inp, ushortt* __restrict__ inpbf) {
  __shared__ float lds[32][33];
  int bid = blockIdx.x;
  int tid = threadIdx.x;
  if (bid < 2048) {
    // relpack: g in [0, 524288)
    int g = bid * 256 + tid;
    const int4* r4 = (const int4*)rel;
    const int4* m4 = (const int4*)msk;
    int4 r = r4[g];
    int4 m = m4[g];
    int b = g >> 18;
    int rem = g & 262143;
    int i = rem >> 8;
    int j4 = (rem & 255) << 2;
    size_t base = ((size_t)b << 20) + ((size_t)(i >> 3) << 13) + (i & 7);
    relc2[base + ((size_t)(j4 + 0) << 3)] = (unsigned char)(m.x ? 128 : r.x);
    relc2[base + ((size_t)(j4 + 1) << 3)] = (unsigned char)(m.y ? 128 : r.y);
    relc2[base + ((size_t)(j4 + 2) << 3)] = (unsigned char)(m.z ? 128 : r.z);
    relc2[base + ((size_t)(j4 + 3) << 3)] = (unsigned char)(m.w ? 128 : r.w);
    if (g < 3200) {
      int d = g / 100, rr = g - d * 100;
      EvT[d * 100 + rr] = Ev[(rr << 5) + d];
    }
    if (g < 3584) {
      int rr = g >> 5, d = g & 31;
      ekbf[g] = (rr < 100) ? f2bf(Ek[(rr << 5) + d]) : (ushortt)0;
    }
  } else if (bid < 2304) {
    // cvt_bf: inp fp32 -> bf16, 524288 elems, 8/thread
    int idx = ((bid - 2048) * 256 + tid) * 8;
    float4 f0 = *(const float4*)(inp + idx);
    float4 f1 = *(const float4*)(inp + idx + 4);
    uint4 u;
    u.x = pk2(f0.x, f0.y); u.y = pk2(f0.z, f0.w);
    u.z = pk2(f1.x, f1.y); u.w = pk2(f1.z, f1.w);
    *(uint4*)(inpbf + idx) = u;
  } else {
    // wcvt: 32x32 transpose tiles. 768 tiles/layer:
    //  t<256: Wq/Wk/Wv/Wo (K=256,N=256), which=t>>6, 8x8 tiles
    //  t<512: W1 (K=256,N=1024), 8x32 tiles
    //  else : W2 (K=1024,N=256), 32x8 tiles
    int t0 = bid - 2304;                  // 0..1535
    int l = (t0 >= 768) ? 1 : 0;
    int t = t0 - (l ? 768 : 0);
    size_t o_w = (size_t)l * 65536, o_w1 = (size_t)l * 262144;
    ushortt* wl = wbuf + (size_t)l * 786432;
    const float* src;
    ushortt* dst;
    int K, N, tk, tn;
    if (t < 256) {
      int which = t >> 6;
      int tt = t & 63;
      K = 256; N = 256; tk = tt >> 3; tn = tt & 7;
      src = ((which == 0) ? Wq : (which == 1) ? Wk : (which == 2) ? Wv : Wo) + o_w;
      dst = wl + (size_t)which * 65536;
    } else if (t < 512) {
      int tt = t - 256;
      K = 256; N = 1024; tk = tt >> 5; tn = tt & 31;
      src = W1 + o_w1;
      dst = wl + 262144;
    } else {
      int tt = t - 512;
      K = 1024; N = 256; tk = tt >> 3; tn = tt & 7;
      src = W2 + o_w1;
      dst = wl + 524288;
    }
    int c = tid & 31;
    int r4w = (tid >> 5) << 2;            // rows r4w..r4w+3
#pragma unroll
    for (int rr = 0; rr < 4; ++rr) {
      int k = (tk << 5) + r4w + rr;
      lds[r4w + rr][c] = src[(size_t)k * N + (tn << 5) + c];
    }
    __syncthreads();
#pragma unroll
    for (int rr = 0; rr < 4; ++rr) {
      int n = (tn << 5) + r4w + rr;
      int k = (tk << 5) + c;
      dst[(size_t)n * K + k] = f2bf(lds[c][r4w + rr]);
    }
  }
}

// ---------- MFMA GEMM body: 64x64 tile, 4 waves, BK=64, reg double-buffer ----
// kvmode 0: C fp32 / cbf bf16 row-major. 1: bf16 [d][j] (v). 2: bf16 [j][d] (k).
// 3: cbf bf16 [i][d] pre-scaled only (q; no fp32 write).
__device__ __forceinline__ void mgemm_body(
    const ushortt* __restrict__ A, const ushortt* __restrict__ BT,
    const float* __restrict__ bias, size_t boff,
    float* __restrict__ C, ushortt* __restrict__ cbf,
    int m0, int n0, int N, int K, int kbeg, int kend, int relu, int kvmode)
{
  __shared__ ushortt As[64 * 72];   // 9.2 KB, +8 pad keeps b128 reads 2-way max
  __shared__ ushortt Bs[64 * 72];
  int tid = threadIdx.x;
  int wv = tid >> 6, lane = tid & 63;
  int quad = lane >> 4, mr = lane & 15;
  int sm = tid >> 2, k16 = (tid & 3) << 4;

  const ushortt* ap = A + (size_t)(m0 + sm) * K + k16;
  const ushortt* bp = BT + (size_t)(n0 + sm) * K + k16;

  // prefetch round 0
  uint4 ra0 = *(const uint4*)(ap + kbeg);
  uint4 ra1 = *(const uint4*)(ap + kbeg + 8);
  uint4 rb0 = *(const uint4*)(bp + kbeg);
  uint4 rb1 = *(const uint4*)(bp + kbeg + 8);

  f32x4 acc[4] = {};
  for (int k0 = kbeg; k0 < kend; k0 += 64) {
    *(uint4*)(&As[sm * 72 + k16])     = ra0;
    *(uint4*)(&As[sm * 72 + k16 + 8]) = ra1;
    *(uint4*)(&Bs[sm * 72 + k16])     = rb0;
    *(uint4*)(&Bs[sm * 72 + k16 + 8]) = rb1;
    __syncthreads();
    if (k0 + 64 < kend) {   // issue next round; waits hide under MFMAs
      ra0 = *(const uint4*)(ap + k0 + 64);
      ra1 = *(const uint4*)(ap + k0 + 72);
      rb0 = *(const uint4*)(bp + k0 + 64);
      rb1 = *(const uint4*)(bp + k0 + 72);
    }
#pragma unroll
    for (int kh = 0; kh < 2; ++kh) {
      short8 af = *(const short8*)(&As[(wv * 16 + mr) * 72 + (kh << 5) + quad * 8]);
#pragma unroll
      for (int nt = 0; nt < 4; ++nt) {
        short8 bf = *(const short8*)(&Bs[(nt * 16 + mr) * 72 + (kh << 5) + quad * 8]);
        acc[nt] = __builtin_amdgcn_mfma_f32_16x16x32_bf16(af, bf, acc[nt], 0, 0, 0);
      }
    }
    __syncthreads();
  }
#pragma unroll
  for (int nt = 0; nt < 4; ++nt) {
#pragma unroll
    for (int r = 0; r < 4; ++r) {
      int m = m0 + wv * 16 + quad * 4 + r;
      int n = n0 + nt * 16 + mr;
      float v = acc[nt][r];
      if (bias) v += bias[boff + n];
      if (relu) v = fmaxf(v, 0.f);
      if (kvmode == 3) {
        int b = m >> 10, i = m & 1023, h = n >> 5, d = n & 31;
        cbf[(size_t)(((b << 3) + h) * 1024 + i) * 32 + d] =
            f2bf(v * 0.17677669529663687f);
      } else if (kvmode == 1) {
        int b = m >> 10, i = m & 1023, h = n >> 5, d = n & 31;
        cbf[(size_t)(((b << 3) + h) * 32 + d) * 1024 + i] = f2bf(v);
      } else if (kvmode == 2) {
        int b = m >> 10, i = m & 1023, h = n >> 5, d = n & 31;
        cbf[(size_t)(((b << 3) + h) * 1024 + i) * 32 + d] = f2bf(v);
      } else if (cbf) {
        cbf[(size_t)m * N + n] = f2bf(v);
      } else {
        C[(size_t)m * N + n] = v;
      }
    }
  }
}

// split-K aware: gridDim.z = ksplit (1,2,4); z=0 -> C0 (+bias), z>0 -> Cz
__global__ __launch_bounds__(256) void mgemm_k(
    const ushortt* __restrict__ A, const ushortt* __restrict__ BT,
    const float* __restrict__ bias, size_t boff,
    float* __restrict__ C0, float* __restrict__ C1,
    float* __restrict__ C2, float* __restrict__ C3,
    ushortt* __restrict__ cbf, int N, int K, int relu)
{
  int kidx = blockIdx.z;
  int kc = K / gridDim.z;
  int kbeg = kidx * kc;
  float* C = (kidx == 0) ? C0 : (kidx == 1) ? C1 : (kidx == 2) ? C2 : C3;
  mgemm_body(A, BT, kidx ? nullptr : bias, boff, C, cbf,
             blockIdx.y * 64, blockIdx.x * 64, N, K, kbeg, kbeg + kc, relu, 0);
}

// fused QKV: sel 0 -> qbf bf16 scaled [i][d]; 1 -> k bf16 [j][d]; 2 -> v bf16 [d][j]
__global__ __launch_bounds__(256) void mqkv_k(
    const ushortt* __restrict__ xbf, const ushortt* __restrict__ WT,
    ushortt* __restrict__ qbf, ushortt* __restrict__ kbf,
    ushortt* __restrict__ vTbf)
{
  int sel = blockIdx.x >> 2;
  const ushortt* BT = WT + (size_t)sel * 65536;
  int mode = (sel == 0) ? 3 : (sel == 1) ? 2 : 1;
  mgemm_body(xbf, BT, nullptr, 0, nullptr,
             (sel == 0) ? qbf : (sel == 1) ? kbf : vTbf,
             blockIdx.y * 64, (blockIdx.x & 3) * 64, 256, 256, 0, 256, 0, mode);
}

// ---------- MFMA attention: block = (b, h, 8 i's), 4 waves, ~23.1 KB LDS ----
// XCD-locality swizzle: xcd=bid&7 owns 2 (b,h) groups (same b) -> K/V/relc2
// L2-resident per XCD. expq via MFMA from ekbf; no Ek/qs staging phase.
__global__ __launch_bounds__(256) void attn_mf8_k(
    const ushortt* __restrict__ qbf, const ushortt* __restrict__ kbf,
    const ushortt* __restrict__ vTbf, const ushortt* __restrict__ ekbf,
    const float* __restrict__ EvT, const unsigned char* __restrict__ relc2,
    ushortt* __restrict__ out)
{
  __shared__ __align__(16) ushortt pbf[8 * 1028];  // 16.4 KB
  __shared__ float expq[800];          // 3.2 KB; pvpart/pvtot overlay after (3)
  __shared__ float wbin[8 * 108];      // 3.4 KB; stride 108: 16B-aligned rows

  int tid = threadIdx.x;
  int wv = tid >> 6, lane = tid & 63;
  int quad = lane >> 4, mr = lane & 15;
  // XCD-locality decode (bijective over 2048): each XCD -> 2 (b,h) groups
  int raw = blockIdx.x;
  int xcd = raw & 7;
  int seq = raw >> 3;                  // 0..255
  int gh = (xcd << 1) + (seq >> 7);    // 0..15 = b*8+h
  int tile = seq & 127;
  int h = gh & 7;
  int b = gh >> 3;
  int i0 = tile << 3;

  // rel codes: relc2[b][tile][j][i8]; lane's 4 rows per iter = one dword.
  int iqsel = quad & 1;
  int iq = iqsel << 2;
  int jofs = ((quad >> 1) << 4) + mr;
  int jbase = wv << 8;
  const unsigned int* rc2 =
      (const unsigned int*)(relc2 + (((size_t)(b << 7) + tile) << 13));
  unsigned int rcw[8];
#pragma unroll
  for (int t = 0; t < 8; ++t)
    rcw[t] = rc2[(((jbase + (t << 5) + jofs)) << 1) + iqsel];

  for (int p = tid; p < 864; p += 256) wbin[p] = 0.f;

  // q frag: one 16B load (qbf pre-scaled bf16, rows 8..15 dup rows 0..7)
  const ushortt* qsrc = qbf + ((size_t)gh << 15);
  short8 qf = *(const short8*)(qsrc + (((size_t)i0 + (mr & 7)) << 5) + quad * 8);

  const ushortt* ks = kbf + ((size_t)gh << 15);   // [j][d]
  const ushortt* vs = vTbf + ((size_t)gh << 15);  // [d][j]
  short8 kfa = *(const short8*)(ks + ((size_t)(jbase + mr) << 5) + quad * 8);
  short8 kfb = *(const short8*)(ks + ((size_t)(jbase + 16 + mr) << 5) + quad * 8);

  // expq via MFMA: r-tiles of 16; wave wv does rt = wv, wv+4 (7 tiles total).
  // C layout: lane holds C[i=quad*4+reg][r=mr]; quads 2,3 dup (A rows 8-15).
#pragma unroll
  for (int tsel = 0; tsel < 2; ++tsel) {
    int rt = wv + (tsel << 2);
    if (rt <= 6) {
      int r0 = rt << 4;
      short8 ekf = *(const short8*)(ekbf + ((size_t)(r0 + mr) << 5) + quad * 8);
      f32x4 z = {};
      f32x4 eq = __builtin_amdgcn_mfma_f32_16x16x32_bf16(qf, ekf, z, 0, 0, 0);
      if (quad < 2) {
#pragma unroll
        for (int r = 0; r < 4; ++r) {
          int i = quad * 4 + r;
          int rr = r0 + mr;
          if (rr < 100) expq[i * 100 + rr] = __expf(eq[r]);
        }
      }
    }
  }
  __syncthreads();  // (1) expq + wbin ready

  // ---- scores: wave wv covers j-quarter (256 j's) as 8 double-tiles ----
#pragma unroll
  for (int t = 0; t < 8; ++t) {
    int j0 = jbase + (t << 5);
    short8 ka = kfa, kb = kfb;
    if (t < 7) {
      kfa = *(const short8*)(ks + ((size_t)(j0 + 32 + mr) << 5) + quad * 8);
      kfb = *(const short8*)(ks + ((size_t)(j0 + 48 + mr) << 5) + quad * 8);
    }
    f32x4 z = {};
    f32x4 sa = __builtin_amdgcn_mfma_f32_16x16x32_bf16(qf, ka, z, 0, 0, 0);
    f32x4 sb = __builtin_amdgcn_mfma_f32_16x16x32_bf16(qf, kb, z, 0, 0, 0);
    int j = j0 + jofs;
    unsigned int w = rcw[t];
#pragma unroll
    for (int r = 0; r < 4; ++r) {
      int i = iq + r;
      float sv = (quad >= 2) ? sb[r] : sa[r];
      unsigned int c = (w >> (r << 3)) & 255u;
      float p = 0.f;
      if (c < 128u) {
        p = __expf(sv) * expq[i * 100 + (int)c];
        atomicAdd(&wbin[i * 108 + (int)c], p);
      }
      pbf[i * 1028 + j] = f2bf(p);
    }
  }
  __syncthreads();  // (3) pbf, wbin complete

  // ---- PV: ntile = wv&1 (d0), khalf = wv>>1 (k0); A rows 8..15 alias 0..7 ----
  float* pvpart = expq;        // [2][8][16]
  float* pvtot  = expq + 256;  // [8][32]
  int d0 = (wv & 1) << 4;
  int k0 = (wv >> 1) << 9;
  int prow = (mr & 7) * 1028;
  f32x4 acc0 = {}, acc1 = {};
  short8 vf = *(const short8*)(vs + ((size_t)(d0 + mr) << 10) + k0 + quad * 8);
#pragma unroll
  for (int kt = 0; kt < 16; ++kt) {
    int kk = k0 + (kt << 5);
    short8 vcur = vf;
    if (kt < 15)
      vf = *(const short8*)(vs + ((size_t)(d0 + mr) << 10) + k0 + ((kt + 1) << 5) + quad * 8);
    short8 pf = *(const short8*)(&pbf[prow + kk + quad * 8]);
    if (kt & 1)
      acc1 = __builtin_amdgcn_mfma_f32_16x16x32_bf16(pf, vcur, acc1, 0, 0, 0);
    else
      acc0 = __builtin_amdgcn_mfma_f32_16x16x32_bf16(pf, vcur, acc0, 0, 0, 0);
  }
  f32x4 acc;
#pragma unroll
  for (int r = 0; r < 4; ++r) acc[r] = acc0[r] + acc1[r];
  if (wv >= 2 && quad < 2) {
#pragma unroll
    for (int r = 0; r < 4; ++r)
      pvpart[((wv & 1) << 7) + (quad * 4 + r) * 16 + mr] = acc[r];
  }
  __syncthreads();  // (4)
  if (wv < 2 && quad < 2) {
#pragma unroll
    for (int r = 0; r < 4; ++r) {
      int i = quad * 4 + r;
      pvtot[i * 32 + d0 + mr] = acc[r] + pvpart[((wv & 1) << 7) + i * 16 + mr];
    }
  }
  __syncthreads();  // (5)

  // ---- final: all 256 threads, i = tid>>5, d = tid&31; bf16 out ----
  // denom[i] = sum of all bins (each unmasked p lands in exactly one bin).
  {
    int i = tid >> 5, d = tid & 31;
    const float4* evt = (const float4*)(EvT + d * 100);
    const float4* wb4 = (const float4*)(&wbin[i * 108]);
    float e0 = 0.f, e1 = 0.f, e2 = 0.f, e3 = 0.f;
    float s0 = 0.f, s1 = 0.f, s2 = 0.f, s3 = 0.f;
#pragma unroll
    for (int rq = 0; rq < 25; ++rq) {
      float4 e4 = evt[rq];
      float4 w4 = wb4[rq];
      e0 += w4.x * e4.x; s0 += w4.x;
      e1 += w4.y * e4.y; s1 += w4.y;
      e2 += w4.z * e4.z; s2 += w4.z;
      e3 += w4.w * e4.w; s3 += w4.w;
    }
    float ev = (e0 + e1) + (e2 + e3);
    float den = (s0 + s1) + (s2 + s3);
    out[(((size_t)(b * 1024 + i0 + i) * 8 + h) << 5) + d] =
        f2bf((pvtot[i * 32 + d] + ev) / den);
  }
}

// ---------- residual (+ up to 4 partials) + LayerNorm: one wave per row ----
__global__ __launch_bounds__(256) void ln_k(
    const float* __restrict__ x, const float* __restrict__ o,
    const float* __restrict__ o2, const float* __restrict__ o3,
    const float* __restrict__ o4,
    const float* __restrict__ g, const float* __restrict__ bta, size_t eoff,
    float* __restrict__ xo, ushortt* __restrict__ xbf, float* __restrict__ fout)
{
  int tid = threadIdx.x;
  int lane = tid & 63;
  int row = (blockIdx.x << 2) + (tid >> 6);
  int col = lane << 2;
  size_t base = (size_t)row * 256 + col;

  float4 r = *(const float4*)(x + base);
  float4 ov = *(const float4*)(o + base);
  r.x += ov.x; r.y += ov.y; r.z += ov.z; r.w += ov.w;
  if (o2) {
    float4 v2 = *(const float4*)(o2 + base);
    r.x += v2.x; r.y += v2.y; r.z += v2.z; r.w += v2.w;
  }
  if (o3) {
    float4 v3 = *(const float4*)(o3 + base);
    r.x += v3.x; r.y += v3.y; r.z += v3.z; r.w += v3.w;
  }
  if (o4) {
    float4 v4 = *(const float4*)(o4 + base);
    r.x += v4.x; r.y += v4.y; r.z += v4.z; r.w += v4.w;
  }
  float s = (r.x + r.y) + (r.z + r.w);
  s += __shfl_xor(s, 1, 64);
  s += __shfl_xor(s, 2, 64);
  s += __shfl_xor(s, 4, 64);
  s += __shfl_xor(s, 8, 64);
  s += __shfl_xor(s, 16, 64);
  s += __shfl_xor(s, 32, 64);
  float mean = s * (1.f / 256.f);
  float dx = r.x - mean, dy = r.y - mean, dz = r.z - mean, dw = r.w - mean;
  float sq = (dx * dx + dy * dy) + (dz * dz + dw * dw);
  sq += __shfl_xor(sq, 1, 64);
  sq += __shfl_xor(sq, 2, 64);
  sq += __shfl_xor(sq, 4, 64);
  sq += __shfl_xor(sq, 8, 64);
  sq += __shfl_xor(sq, 16, 64);
  sq += __shfl_xor(sq, 32, 64);
  float rs = rsqrtf(sq * (1.f / 256.f) + 1e-5f);
  float4 gv = *(const float4*)(g + eoff + col);
  float4 bv = *(const float4*)(bta + eoff + col);
  float4 val;
  val.x = dx * rs * gv.x + bv.x;
  val.y = dy * rs * gv.y + bv.y;
  val.z = dz * rs * gv.z + bv.z;
  val.w = dw * rs * gv.w + bv.w;
  *(float4*)(xo + base) = val;
  uint2 u;
  u.x = pk2(val.x, val.y);
  u.y = pk2(val.z, val.w);
  *(uint2*)(xbf + base) = u;
  if (fout) *(float4*)(fout + base) = val;
}

extern "C" void kernel_launch(void* const* d_in, const int* in_sizes, int n_in,
                              void* d_out, int out_size, void* d_ws, size_t ws_size,
                              hipStream_t stream) {
  const float* inp  = (const float*)d_in[0];
  const float* Wq   = (const float*)d_in[1];
  const float* Wk   = (const float*)d_in[2];
  const float* Wv   = (const float*)d_in[3];
  const float* Wo   = (const float*)d_in[4];
  const float* bo   = (const float*)d_in[5];
  const float* W1   = (const float*)d_in[6];
  const float* b1   = (const float*)d_in[7];
  const float* W2   = (const float*)d_in[8];
  const float* b2   = (const float*)d_in[9];
  const float* ln1g = (const float*)d_in[10];
  const float* ln1b = (const float*)d_in[11];
  const float* ln2g = (const float*)d_in[12];
  const float* ln2b = (const float*)d_in[13];
  const float* Ek   = (const float*)d_in[14];
  const float* Ev   = (const float*)d_in[15];
  const int*   rel  = (const int*)d_in[16];
  const int*   msk  = (const int*)d_in[17];

  const size_t SZ = 524288;  // 2048*256
  float* x        = (float*)d_ws;               // 2 MB fp32
  float* q        = x + SZ;                     // 2 MB fp32 (dead; layout keep)
  ushortt* kbf    = (ushortt*)(q + SZ);         // 1 MB bf16 [j][d]
  ushortt* vTbf   = kbf + SZ;                   // 1 MB bf16 [d][j]
  ushortt* attnbf = vTbf + SZ;                  // 1 MB bf16 attn out
  ushortt* xbf    = attnbf + SZ;                // 1 MB bf16 x
  float* tmp      = (float*)(xbf + SZ);         // 2 MB fp32 partial 0
  ushortt* wbuf   = (ushortt*)(tmp + SZ);       // 3 MB (both layers' weights)
  unsigned char* relc2 = (unsigned char*)(wbuf + 1572864);  // 2 MB packed rel
  float* EvT      = (float*)(relc2 + 2097152);  // 12.8 KB (pad to 16 KB)
  float* tmp2     = (float*)((char*)EvT + 16384); // 2 MB fp32 partial 1
  ushortt* inpbf  = (ushortt*)tmp2;             // alias: dead before wo writes tmp2
  ushortt* qbf    = (ushortt*)(tmp2 + SZ);      // 1 MB bf16 q (scaled)
  ushortt* ekbf   = qbf + SZ;                   // 7 KB bf16 Ek [112][32]
  float* tmp3     = (float*)((char*)ekbf + 16384); // 2 MB fp32 partial 2
  float* tmp4     = tmp3 + SZ;                  // 2 MB fp32 partial 3
  ushortt* ffh    = (ushortt*)q;                // 4 MB alias over q+kbf+vTbf

  dim3 blk(256);
  setup_k<<<3840, blk, 0, stream>>>(Wq, Wk, Wv, Wo, W1, W2, wbuf,
                                    rel, msk, relc2, Ev, EvT, Ek, ekbf,
                                    inp, inpbf);

  for (int l = 0; l < 2; ++l) {
    size_t o_b  = (size_t)l * 256;
    size_t o_b1 = (size_t)l * 1024;
    const ushortt* xinbf = (l == 0) ? inpbf : xbf;
    const float* xin = (l == 0) ? inp : x;
    ushortt* wl = wbuf + (size_t)l * 786432;

    mqkv_k<<<dim3(12, 32), blk, 0, stream>>>(xinbf, wl, qbf, kbf, vTbf);

    attn_mf8_k<<<2048, blk, 0, stream>>>(qbf, kbf, vTbf, ekbf, EvT,
                                         relc2, attnbf);

    // wo-proj: split-K x4 -> 512 blocks, 1 K-round each
    mgemm_k<<<dim3(4, 32, 4), blk, 0, stream>>>(attnbf, wl + 196608,
                                                bo, o_b, tmp, tmp2, tmp3, tmp4,
                                                nullptr, 256, 256, 0);
    ln_k<<<512, blk, 0, stream>>>(xin, tmp, tmp2, tmp3, tmp4,
                                  ln1g, ln1b, o_b, x, xbf, nullptr);

    mgemm_k<<<dim3(16, 32, 1), blk, 0, stream>>>(xbf, wl + 262144,
                                                 b1, o_b1, nullptr, nullptr,
                                                 nullptr, nullptr, ffh,
                                                 1024, 256, 1);
    // ffn2: split-K x4 -> 512 blocks, 4 K-rounds each
    mgemm_k<<<dim3(4, 32, 4), blk, 0, stream>>>(ffh, wl + 524288,
                                                b2, o_b, tmp, tmp2, tmp3, tmp4,
                                                nullptr, 256, 1024, 0);
    ln_k<<<512, blk, 0, stream>>>(x, tmp, tmp2, tmp3, tmp4,
                                  ln2g, ln2b, o_b, x, xbf,
                                  (l == 1) ? (float*)d_out : nullptr);
  }
}